// Round 4
// baseline (344.719 us; speedup 1.0000x reference)
//
#include <hip/hip_runtime.h>
#include <hip/hip_bf16.h>
#include <stdint.h>

// Problem constants: N=16, T=512, H=C=O=64, K=9, E=256
typedef float f32x4 __attribute__((ext_vector_type(4)));
typedef __bf16 bf16x8 __attribute__((ext_vector_type(8)));
typedef __bf16 bf16x4 __attribute__((ext_vector_type(4)));
typedef unsigned short u16;
typedef unsigned int u32;

__device__ __forceinline__ u16 f2bf(float f) {
    u32 u = __float_as_uint(f);
    u32 r = (u + 0x7fffu + ((u >> 16) & 1u)) >> 16;
    return (u16)r;
}

// DPP row_ror:N within 16-lane rows — VALU-pipe lane rotate (no LDS traffic)
template <int CTRL>
__device__ __forceinline__ float rrot(float x) {
    int r = __builtin_amdgcn_update_dpp(0, __builtin_bit_cast(int, x), CTRL, 0xF, 0xF, false);
    return __builtin_bit_cast(float, r);
}
__device__ __forceinline__ float rowsum16(float p) {
    p += rrot<0x128>(p);  // ror 8
    p += rrot<0x124>(p);  // ror 4
    p += rrot<0x122>(p);  // ror 2
    p += rrot<0x121>(p);  // ror 1
    return p;
}

// ---------------------------------------------------------------- k_attn
// Block = (n, 4 t's). Coalesced X loads; DPP row reduction for a1/a2; adj
// built in LDS from edges (transposed adjT[k][h]); wave w owns t = tg*4+w.
// WB: also emit bf16 copy of X (same flattening) for k_gcn's staging.
// Appended blocks: weight pack (BN-gamma pre-scaled) + aux constants.
#define NB_ATTN 2048

template <bool WB>
__global__ __launch_bounds__(256) void k_attn(
    const float* __restrict__ X, const int* __restrict__ edges,
    const float* __restrict__ w1g, const float* __restrict__ b1g,
    const float* __restrict__ w2g, const float* __restrict__ b2g,
    const float* __restrict__ Wlin, const float* __restrict__ Wtcn,
    const float* __restrict__ blin, const float* __restrict__ g1,
    const float* __restrict__ be1, const float* __restrict__ btcn,
    const float* __restrict__ g2, const float* __restrict__ be2,
    u16* __restrict__ wlin_p, u16* __restrict__ wtcn_p,
    float* __restrict__ aux, float* __restrict__ diag,
    u16* __restrict__ Xbf) {
    const int tid = threadIdx.x;
    const int bid = blockIdx.x;
    const float rsf = 1.0f / sqrtf(1.0f + 1e-5f);

    if (bid >= NB_ATTN) {
        // ---- weight pack, MFMA B-fragment order, BN scale folded in ----
        int idx = (bid - NB_ATTN) * 256 + tid;
        if (idx < 4096) {
            int jj = idx & 7, l = (idx >> 3) & 63, j = (idx >> 9) & 3, s = idx >> 11;
            int o = j * 16 + (l & 15);
            int c = s * 32 + (l >> 4) * 8 + jj;
            wlin_p[idx] = f2bf(Wlin[o * 64 + c] * (g1[o] * rsf));
        }
        int i2 = idx - 4096;
        if (i2 >= 0 && i2 < 36864) {
            int jj = i2 & 7, l = (i2 >> 3) & 63, j = (i2 >> 9) & 3, s = (i2 >> 11) & 1, kk = i2 >> 12;
            int o = j * 16 + (l & 15);
            int op = s * 32 + (l >> 4) * 8 + jj;
            wtcn_p[i2] = f2bf(Wtcn[(o * 64 + op) * 9 + kk] * (g2[o] * rsf));
        }
        if (idx >= 40960 && tid < 64) {
            // aux: [0,64) blin*s1; [64,128) be1; [128,192) btcn*s2+be2
            aux[tid] = blin[tid] * g1[tid] * rsf;
            aux[64 + tid] = be1[tid];
            aux[128 + tid] = btcn[tid] * g2[tid] * rsf + be2[tid];
        }
        return;
    }

    // adjT[k*65 + h] = adj[h][k]; bank (k+h)&31 -> 2-way across 64 lanes (free)
    __shared__ __align__(16) float adjT[64 * 65];
    __shared__ __align__(16) float A1s[4][64], A2s[4][64];

    const int n = bid >> 7;        // 128 blocks per n
    const int tg = bid & 127;
    const int w = tid >> 6, l = tid & 63;
    const int t = tg * 4 + w;      // one t per wave
    const int c4 = l & 15, q = l >> 4;

    {
        f32x4 z4 = {0.f, 0.f, 0.f, 0.f};
        for (int i = tid; i < 1040; i += 256) *(f32x4*)(&adjT[i * 4]) = z4;
    }
    __syncthreads();
    {
        int r = edges[n * 512 + tid];        // edges[n][0][e]
        int c = edges[n * 512 + 256 + tid];  // edges[n][1][e]
        atomicAdd(&adjT[c * 65 + r], 1.0f);  // transposed store
    }

    // ---- a1/a2: coalesced loads + DPP row reduction; optional bf16 X copy
    const float* Xt = X + (size_t)(n * 512 + t) * 4096;
    u16* Xbt = WB ? (Xbf + (size_t)(n * 512 + t) * 4096) : nullptr;
    const float4 w1v = *(const float4*)(w1g + c4 * 4);
    const float4 w2v = *(const float4*)(w2g + c4 * 4);
    float a1h = 0.f, a2h = 0.f;
#pragma unroll 8
    for (int i = 0; i < 16; i++) {
        float4 xv = *(const float4*)(Xt + (i * 64 + l) * 4);  // 1KB/instr contiguous
        if (WB) {
            bf16x4 pk;
            pk[0] = (__bf16)xv.x; pk[1] = (__bf16)xv.y;
            pk[2] = (__bf16)xv.z; pk[3] = (__bf16)xv.w;
            *(bf16x4*)(Xbt + (i * 64 + l) * 4) = pk;  // coalesced 8B/lane
        }
        float p1 = xv.x * w1v.x + xv.y * w1v.y + xv.z * w1v.z + xv.w * w1v.w;
        float p2 = xv.x * w2v.x + xv.y * w2v.y + xv.z * w2v.z + xv.w * w2v.w;
        p1 = rowsum16(p1);
        p2 = rowsum16(p2);
        if (c4 == i) { a1h = p1; a2h = p2; }
    }
    {
        int hh = c4 * 4 + q;  // the h this lane holds
        A1s[w][hh] = a1h + b1g[0];
        A2s[w][hh] = a2h + b2g[0];
    }
    __syncthreads();  // covers adj atomics + A1s/A2s

    // ---- softmax over k: lane l <-> h=l; A1s read as broadcast float4
    {
        float a2 = A2s[w][l];
        float num = 0.f, den = 0.f;
#pragma unroll
        for (int k4 = 0; k4 < 16; k4++) {
            float4 a1v = *(const float4*)(&A1s[w][k4 * 4]);
#pragma unroll
            for (int j = 0; j < 4; j++) {
                int k = k4 * 4 + j;
                float s = ((const float*)&a1v)[j] + a2;
                s = fmaxf(s, 0.01f * s);  // leaky_relu(0.01)
                float e = __expf(s);
                den += e;
                num = fmaf(adjT[k * 65 + l], e, num);
            }
        }
        diag[((size_t)(n * 64 + l)) * 512 + t] = num / den + 1.0f;
    }
}

// ---------------------------------------------------------------- k_gcn_tcn
// One block per (n, h, quarter-T=128). BF: stage from pre-converted bf16 X
// (pure uint2 copy, half the fetch bytes, no cvt); else f32+cvt fallback.
// Support GEMM in place (BN1 pre-scaled), barrier, residual prefetch issued
// BEFORE the K=9 conv GEMM (latency hides under 144 MFMAs), epilogue.
template <bool BF>
__global__ __launch_bounds__(256) void k_gcn_tcn(
    const float* __restrict__ X, const u16* __restrict__ Xbf,
    const float* __restrict__ diag,
    const u16* __restrict__ wlin_p, const u16* __restrict__ wtcn_p,
    const float* __restrict__ aux, float* __restrict__ out) {
    __shared__ __align__(16) u16 As[144 * 72];  // row r <-> t = tb-4+r, pad 72
    __shared__ float DGs[144];

    const int tid = threadIdx.x;
    const int bid = blockIdx.x;
    const int n = bid >> 8, h = (bid >> 2) & 63, tb = (bid & 3) * 128;

    // stage (zero halo outside [0,512))
    if (BF) {
        const u16* Xb = Xbf + (size_t)(n * 512) * 4096 + h * 64;  // + t*4096 + c
#pragma unroll
        for (int i = 0; i < 9; i++) {
            int idx = tid + 256 * i;  // 144 rows * 16 quads
            int r = idx >> 4, c4 = idx & 15;
            int tg = tb - 4 + r;
            uint2 d = make_uint2(0u, 0u);
            if (tg >= 0 && tg < 512) d = *(const uint2*)(Xb + (size_t)tg * 4096 + c4 * 4);
            *(uint2*)(&As[r * 72 + c4 * 4]) = d;
        }
    } else {
        const float* Xbase = X + ((size_t)(n * 512) * 64 + h) * 64;
#pragma unroll
        for (int i = 0; i < 9; i++) {
            int idx = tid + 256 * i;
            int r = idx >> 4, c4 = idx & 15;
            int tg = tb - 4 + r;
            float4 xv = make_float4(0.f, 0.f, 0.f, 0.f);
            if (tg >= 0 && tg < 512) xv = *(const float4*)(Xbase + (size_t)tg * 4096 + c4 * 4);
            bf16x4 pk;
            pk[0] = (__bf16)xv.x; pk[1] = (__bf16)xv.y;
            pk[2] = (__bf16)xv.z; pk[3] = (__bf16)xv.w;
            *(bf16x4*)(&As[r * 72 + c4 * 4]) = pk;
        }
    }
    if (tid < 144) {
        int tg = tb - 4 + tid;
        DGs[tid] = (tg >= 0 && tg < 512) ? diag[((size_t)(n * 64 + h)) * 512 + tg] : 0.f;
    }

    const int w = tid >> 6, l = tid & 63;
    const int col = l & 15, q = l >> 4;
    const f32x4 zv = {0.f, 0.f, 0.f, 0.f};

    // per-lane epilogue constants (L2-resident aux; hides under stage)
    float blp[4], bb1[4], cc2[4];
#pragma unroll
    for (int j = 0; j < 4; j++) {
        int o = 16 * j + col;
        blp[j] = aux[o];
        bb1[j] = aux[64 + o];
        cc2[j] = aux[128 + o];
    }
    __syncthreads();

    // support GEMM, z written in place over X rows (wave-private m-tiles)
    for (int mt = w; mt < 9; mt += 4) {
        f32x4 acc[4] = {zv, zv, zv, zv};
#pragma unroll
        for (int s = 0; s < 2; s++) {
            bf16x8 a = *(const bf16x8*)(&As[(16 * mt + col) * 72 + s * 32 + q * 8]);
#pragma unroll
            for (int j = 0; j < 4; j++) {
                bf16x8 b = *(const bf16x8*)(&wlin_p[((s * 4 + j) * 64 + l) * 8]);
                acc[j] = __builtin_amdgcn_mfma_f32_16x16x32_bf16(a, b, acc[j], 0, 0, 0);
            }
        }
#pragma unroll
        for (int j = 0; j < 4; j++) {
#pragma unroll
            for (int rr = 0; rr < 4; rr++) {
                int row = 16 * mt + q * 4 + rr;
                int tg = tb - 4 + row;
                float v = fmaf(acc[j][rr] + blp[j], DGs[row], bb1[j]);
                v = v > 0.f ? v : 0.f;
                if (tg < 0 || tg >= 512) v = 0.f;  // conv halo must be zero
                __bf16 bv = (__bf16)v;
                As[row * 72 + 16 * j + col] = __builtin_bit_cast(u16, bv);
            }
        }
    }
    __syncthreads();

    // residual prefetch: issue all 32 loads now; consumed after the conv
    // GEMM -> ~900cy latency hides under 144 MFMAs
    float res[2][4][4];
#pragma unroll
    for (int mt = 0; mt < 2; mt++)
#pragma unroll
        for (int rr = 0; rr < 4; rr++) {
            int tt = tb + 32 * w + 16 * mt + 4 * q + rr;
#pragma unroll
            for (int j = 0; j < 4; j++)
                res[mt][j][rr] = X[((size_t)(n * 512 + tt) * 64 + h) * 64 + 16 * j + col];
        }

    // temporal conv: wave w -> output local rows [32w, 32w+32)
    f32x4 acc2[2][4];
#pragma unroll
    for (int mt = 0; mt < 2; mt++)
#pragma unroll
        for (int j = 0; j < 4; j++) acc2[mt][j] = zv;

    for (int kk = 0; kk < 9; kk++) {
#pragma unroll
        for (int s = 0; s < 2; s++) {
            bf16x8 b[4];
#pragma unroll
            for (int j = 0; j < 4; j++)
                b[j] = *(const bf16x8*)(&wtcn_p[(((kk * 2 + s) * 4 + j) * 64 + l) * 8]);
            bf16x8 a[2];
#pragma unroll
            for (int mt = 0; mt < 2; mt++) {
                int row = 32 * w + 16 * mt + col + kk;  // <= 135
                a[mt] = *(const bf16x8*)(&As[row * 72 + s * 32 + q * 8]);
            }
#pragma unroll
            for (int mt = 0; mt < 2; mt++)
#pragma unroll
                for (int j = 0; j < 4; j++)
                    acc2[mt][j] = __builtin_amdgcn_mfma_f32_16x16x32_bf16(a[mt], b[j], acc2[mt][j], 0, 0, 0);
        }
    }

    // epilogue: +const (BN2 pre-folded) + prefetched residual + ReLU
#pragma unroll
    for (int mt = 0; mt < 2; mt++) {
#pragma unroll
        for (int rr = 0; rr < 4; rr++) {
            int tt = tb + 32 * w + 16 * mt + 4 * q + rr;
#pragma unroll
            for (int j = 0; j < 4; j++) {
                size_t off = ((size_t)(n * 512 + tt) * 64 + h) * 64 + 16 * j + col;
                float v = acc2[mt][j][rr] + cc2[j] + res[mt][j][rr];
                out[off] = v > 0.f ? v : 0.f;
            }
        }
    }
}

// ---------------------------------------------------------------- launch
extern "C" void kernel_launch(void* const* d_in, const int* in_sizes, int n_in,
                              void* d_out, int out_size, void* d_ws, size_t ws_size,
                              hipStream_t stream) {
    const float* X    = (const float*)d_in[0];
    const int*  edges = (const int*)d_in[1];
    const float* w1   = (const float*)d_in[2];
    const float* b1   = (const float*)d_in[3];
    const float* w2   = (const float*)d_in[4];
    const float* b2   = (const float*)d_in[5];
    const float* Wlin = (const float*)d_in[6];
    const float* blin = (const float*)d_in[7];
    const float* g1   = (const float*)d_in[8];
    const float* be1  = (const float*)d_in[9];
    const float* Wtcn = (const float*)d_in[10];
    const float* btcn = (const float*)d_in[11];
    const float* g2   = (const float*)d_in[12];
    const float* be2  = (const float*)d_in[13];
    float* out = (float*)d_out;

    char* ws = (char*)d_ws;
    u16*   wlin_p = (u16*)ws;                          // 8192 B
    u16*   wtcn_p = (u16*)(ws + 8192);                 // 73728 B
    float* aux    = (float*)(ws + 8192 + 73728);       // 1024 B
    float* diag   = (float*)(ws + 8192 + 73728 + 1024);// 2097152 B
    u16*   Xbf    = (u16*)(ws + 8192 + 73728 + 1024 + 2097152);  // 67108864 B
    const size_t need = 8192 + 73728 + 1024 + 2097152 + 67108864;

    if (ws_size >= need) {
        hipLaunchKernelGGL((k_attn<true>), dim3(NB_ATTN + 161), dim3(256), 0, stream,
                           X, edges, w1, b1, w2, b2, Wlin, Wtcn,
                           blin, g1, be1, btcn, g2, be2,
                           wlin_p, wtcn_p, aux, diag, Xbf);
        hipLaunchKernelGGL((k_gcn_tcn<true>), dim3(16 * 64 * 4), dim3(256), 0, stream,
                           X, Xbf, diag, wlin_p, wtcn_p, aux, out);
    } else {
        hipLaunchKernelGGL((k_attn<false>), dim3(NB_ATTN + 161), dim3(256), 0, stream,
                           X, edges, w1, b1, w2, b2, Wlin, Wtcn,
                           blin, g1, be1, btcn, g2, be2,
                           wlin_p, wtcn_p, aux, diag, (u16*)nullptr);
        hipLaunchKernelGGL((k_gcn_tcn<false>), dim3(16 * 64 * 4), dim3(256), 0, stream,
                           X, (const u16*)nullptr, diag, wlin_p, wtcn_p, aux, out);
    }
}

// Round 5
// 343.439 us; speedup vs baseline: 1.0037x; 1.0037x over previous
//
#include <hip/hip_runtime.h>
#include <hip/hip_bf16.h>
#include <stdint.h>

// Problem constants: N=16, T=512, H=C=O=64, K=9, E=256
typedef float f32x4 __attribute__((ext_vector_type(4)));
typedef __bf16 bf16x8 __attribute__((ext_vector_type(8)));
typedef __bf16 bf16x4 __attribute__((ext_vector_type(4)));
typedef unsigned short u16;
typedef unsigned int u32;

__device__ __forceinline__ u16 f2bf(float f) {
    u32 u = __float_as_uint(f);
    u32 r = (u + 0x7fffu + ((u >> 16) & 1u)) >> 16;
    return (u16)r;
}

// DPP row_ror:N within 16-lane rows — VALU-pipe lane rotate (no LDS traffic)
template <int CTRL>
__device__ __forceinline__ float rrot(float x) {
    int r = __builtin_amdgcn_update_dpp(0, __builtin_bit_cast(int, x), CTRL, 0xF, 0xF, false);
    return __builtin_bit_cast(float, r);
}
__device__ __forceinline__ float rowsum16(float p) {
    p += rrot<0x128>(p);  // ror 8
    p += rrot<0x124>(p);  // ror 4
    p += rrot<0x122>(p);  // ror 2
    p += rrot<0x121>(p);  // ror 1
    return p;
}

// ---------------------------------------------------------------- k_attn
// (r3-proven version, unchanged) Block = (n, 4 t's). Coalesced X loads; DPP
// row reduction for a1/a2; adj built in LDS from edges (transposed adjT);
// appended blocks: weight pack (BN-gamma pre-scaled) + aux constants.
#define NB_ATTN 2048

__global__ __launch_bounds__(256) void k_attn(
    const float* __restrict__ X, const int* __restrict__ edges,
    const float* __restrict__ w1g, const float* __restrict__ b1g,
    const float* __restrict__ w2g, const float* __restrict__ b2g,
    const float* __restrict__ Wlin, const float* __restrict__ Wtcn,
    const float* __restrict__ blin, const float* __restrict__ g1,
    const float* __restrict__ be1, const float* __restrict__ btcn,
    const float* __restrict__ g2, const float* __restrict__ be2,
    u16* __restrict__ wlin_p, u16* __restrict__ wtcn_p,
    float* __restrict__ aux, float* __restrict__ diag) {
    const int tid = threadIdx.x;
    const int bid = blockIdx.x;
    const float rsf = 1.0f / sqrtf(1.0f + 1e-5f);

    if (bid >= NB_ATTN) {
        int idx = (bid - NB_ATTN) * 256 + tid;
        if (idx < 4096) {
            int jj = idx & 7, l = (idx >> 3) & 63, j = (idx >> 9) & 3, s = idx >> 11;
            int o = j * 16 + (l & 15);
            int c = s * 32 + (l >> 4) * 8 + jj;
            wlin_p[idx] = f2bf(Wlin[o * 64 + c] * (g1[o] * rsf));
        }
        int i2 = idx - 4096;
        if (i2 >= 0 && i2 < 36864) {
            int jj = i2 & 7, l = (i2 >> 3) & 63, j = (i2 >> 9) & 3, s = (i2 >> 11) & 1, kk = i2 >> 12;
            int o = j * 16 + (l & 15);
            int op = s * 32 + (l >> 4) * 8 + jj;
            wtcn_p[i2] = f2bf(Wtcn[(o * 64 + op) * 9 + kk] * (g2[o] * rsf));
        }
        if (idx >= 40960 && tid < 64) {
            aux[tid] = blin[tid] * g1[tid] * rsf;
            aux[64 + tid] = be1[tid];
            aux[128 + tid] = btcn[tid] * g2[tid] * rsf + be2[tid];
        }
        return;
    }

    __shared__ __align__(16) float adjT[64 * 65];
    __shared__ __align__(16) float A1s[4][64], A2s[4][64];

    const int n = bid >> 7;
    const int tg = bid & 127;
    const int w = tid >> 6, l = tid & 63;
    const int t = tg * 4 + w;
    const int c4 = l & 15, q = l >> 4;

    {
        f32x4 z4 = {0.f, 0.f, 0.f, 0.f};
        for (int i = tid; i < 1040; i += 256) *(f32x4*)(&adjT[i * 4]) = z4;
    }
    __syncthreads();
    {
        int r = edges[n * 512 + tid];
        int c = edges[n * 512 + 256 + tid];
        atomicAdd(&adjT[c * 65 + r], 1.0f);
    }

    const float* Xt = X + (size_t)(n * 512 + t) * 4096;
    const float4 w1v = *(const float4*)(w1g + c4 * 4);
    const float4 w2v = *(const float4*)(w2g + c4 * 4);
    float a1h = 0.f, a2h = 0.f;
#pragma unroll 8
    for (int i = 0; i < 16; i++) {
        float4 xv = *(const float4*)(Xt + (i * 64 + l) * 4);
        float p1 = xv.x * w1v.x + xv.y * w1v.y + xv.z * w1v.z + xv.w * w1v.w;
        float p2 = xv.x * w2v.x + xv.y * w2v.y + xv.z * w2v.z + xv.w * w2v.w;
        p1 = rowsum16(p1);
        p2 = rowsum16(p2);
        if (c4 == i) { a1h = p1; a2h = p2; }
    }
    {
        int hh = c4 * 4 + q;
        A1s[w][hh] = a1h + b1g[0];
        A2s[w][hh] = a2h + b2g[0];
    }
    __syncthreads();

    {
        float a2 = A2s[w][l];
        float num = 0.f, den = 0.f;
#pragma unroll
        for (int k4 = 0; k4 < 16; k4++) {
            float4 a1v = *(const float4*)(&A1s[w][k4 * 4]);
#pragma unroll
            for (int j = 0; j < 4; j++) {
                int k = k4 * 4 + j;
                float s = ((const float*)&a1v)[j] + a2;
                s = fmaxf(s, 0.01f * s);
                float e = __expf(s);
                den += e;
                num = fmaf(adjT[k * 65 + l], e, num);
            }
        }
        diag[((size_t)(n * 64 + l)) * 512 + t] = num / den + 1.0f;
    }
}

// ---------------------------------------------------------------- k_gcn_tcn
// One block per (n, h, eighth-T=64). Staged rows r=0..79 <-> t=tb-4+r.
// LDS ~12KB -> high residency; __launch_bounds__(256,6) pins >=6 waves/EU.
// G1: 5 m-tiles over 4 waves (support GEMM, z in place, BN1 pre-scaled).
// G2: o-split — wave w computes ALL 64 t-rows for j=w only, so the block
// reads wtcn_p exactly once (72KB vs 288KB) and acc2 is 16 regs.
__global__ __launch_bounds__(256, 6) void k_gcn_tcn(
    const float* __restrict__ X, const float* __restrict__ diag,
    const u16* __restrict__ wlin_p, const u16* __restrict__ wtcn_p,
    const float* __restrict__ aux, float* __restrict__ out) {
    __shared__ __align__(16) u16 As[80 * 72];  // row r <-> t = tb-4+r, pad 72
    __shared__ float DGs[80];

    const int tid = threadIdx.x;
    const int bid = blockIdx.x;
    const int n = bid >> 9, h = (bid >> 3) & 63, tb = (bid & 7) * 64;
    const float* Xbase = X + ((size_t)(n * 512) * 64 + h) * 64;  // + t*4096 + c

    // stage X (f32 -> bf16 via v_cvt_pk), zero outside [0,512)
#pragma unroll
    for (int i = 0; i < 5; i++) {
        int idx = tid + 256 * i;  // 80 rows * 16 quads = 1280
        int r = idx >> 4, c4 = idx & 15;
        int tg = tb - 4 + r;
        float4 xv = make_float4(0.f, 0.f, 0.f, 0.f);
        if (tg >= 0 && tg < 512) xv = *(const float4*)(Xbase + (size_t)tg * 4096 + c4 * 4);
        bf16x4 pk;
        pk[0] = (__bf16)xv.x; pk[1] = (__bf16)xv.y;
        pk[2] = (__bf16)xv.z; pk[3] = (__bf16)xv.w;
        *(bf16x4*)(&As[r * 72 + c4 * 4]) = pk;
    }
    if (tid < 80) {
        int tg = tb - 4 + tid;
        DGs[tid] = (tg >= 0 && tg < 512) ? diag[((size_t)(n * 64 + h)) * 512 + tg] : 0.f;
    }

    const int w = tid >> 6, l = tid & 63;
    const int col = l & 15, q = l >> 4;
    const f32x4 zv = {0.f, 0.f, 0.f, 0.f};

    // per-lane epilogue constants (L2-resident aux; hides under stage)
    float blp[4], bb1[4];
#pragma unroll
    for (int j = 0; j < 4; j++) {
        int o = 16 * j + col;
        blp[j] = aux[o];
        bb1[j] = aux[64 + o];
    }
    const float cc2 = aux[128 + 16 * w + col];  // j=w only (G2 o-split)
    __syncthreads();

    // support GEMM, z written in place over X rows (wave-private m-tiles)
    for (int mt = w; mt < 5; mt += 4) {
        f32x4 acc[4] = {zv, zv, zv, zv};
#pragma unroll
        for (int s = 0; s < 2; s++) {
            bf16x8 a = *(const bf16x8*)(&As[(16 * mt + col) * 72 + s * 32 + q * 8]);
#pragma unroll
            for (int j = 0; j < 4; j++) {
                bf16x8 b = *(const bf16x8*)(&wlin_p[((s * 4 + j) * 64 + l) * 8]);
                acc[j] = __builtin_amdgcn_mfma_f32_16x16x32_bf16(a, b, acc[j], 0, 0, 0);
            }
        }
#pragma unroll
        for (int j = 0; j < 4; j++) {
#pragma unroll
            for (int rr = 0; rr < 4; rr++) {
                int row = 16 * mt + q * 4 + rr;
                int tg = tb - 4 + row;
                float v = fmaf(acc[j][rr] + blp[j], DGs[row], bb1[j]);
                v = v > 0.f ? v : 0.f;
                if (tg < 0 || tg >= 512) v = 0.f;  // conv halo must be zero
                __bf16 bv = (__bf16)v;
                As[row * 72 + 16 * j + col] = __builtin_bit_cast(u16, bv);
            }
        }
    }
    __syncthreads();

    // temporal conv, o-split: wave w -> j=w, all 64 output rows (4 m-tiles)
    f32x4 acc2[4] = {zv, zv, zv, zv};
#pragma unroll
    for (int kk = 0; kk < 9; kk++) {
#pragma unroll
        for (int s = 0; s < 2; s++) {
            bf16x8 b = *(const bf16x8*)(&wtcn_p[(((kk * 2 + s) * 4 + w) * 64 + l) * 8]);
#pragma unroll
            for (int mt = 0; mt < 4; mt++) {
                bf16x8 a = *(const bf16x8*)(&As[(16 * mt + col + kk) * 72 + s * 32 + q * 8]);
                acc2[mt] = __builtin_amdgcn_mfma_f32_16x16x32_bf16(a, b, acc2[mt], 0, 0, 0);
            }
        }
    }

    // epilogue: +const (BN2 pre-folded) + f32 residual (L2-warm from stage) + ReLU
#pragma unroll
    for (int mt = 0; mt < 4; mt++) {
        float res[4];
#pragma unroll
        for (int rr = 0; rr < 4; rr++) {
            int tt = tb + 16 * mt + 4 * q + rr;
            res[rr] = X[((size_t)(n * 512 + tt) * 64 + h) * 64 + 16 * w + col];
        }
#pragma unroll
        for (int rr = 0; rr < 4; rr++) {
            int tt = tb + 16 * mt + 4 * q + rr;
            size_t off = ((size_t)(n * 512 + tt) * 64 + h) * 64 + 16 * w + col;
            float v = acc2[mt][rr] + cc2 + res[rr];
            out[off] = v > 0.f ? v : 0.f;
        }
    }
}

// ---------------------------------------------------------------- launch
extern "C" void kernel_launch(void* const* d_in, const int* in_sizes, int n_in,
                              void* d_out, int out_size, void* d_ws, size_t ws_size,
                              hipStream_t stream) {
    const float* X    = (const float*)d_in[0];
    const int*  edges = (const int*)d_in[1];
    const float* w1   = (const float*)d_in[2];
    const float* b1   = (const float*)d_in[3];
    const float* w2   = (const float*)d_in[4];
    const float* b2   = (const float*)d_in[5];
    const float* Wlin = (const float*)d_in[6];
    const float* blin = (const float*)d_in[7];
    const float* g1   = (const float*)d_in[8];
    const float* be1  = (const float*)d_in[9];
    const float* Wtcn = (const float*)d_in[10];
    const float* btcn = (const float*)d_in[11];
    const float* g2   = (const float*)d_in[12];
    const float* be2  = (const float*)d_in[13];
    float* out = (float*)d_out;

    char* ws = (char*)d_ws;
    u16*   wlin_p = (u16*)ws;                          // 8192 B
    u16*   wtcn_p = (u16*)(ws + 8192);                 // 73728 B
    float* aux    = (float*)(ws + 8192 + 73728);       // 1024 B
    float* diag   = (float*)(ws + 8192 + 73728 + 1024);// 2097152 B

    hipLaunchKernelGGL(k_attn, dim3(NB_ATTN + 161), dim3(256), 0, stream,
                       X, edges, w1, b1, w2, b2, Wlin, Wtcn,
                       blin, g1, be1, btcn, g2, be2,
                       wlin_p, wtcn_p, aux, diag);
    hipLaunchKernelGGL(k_gcn_tcn, dim3(16 * 64 * 8), dim3(256), 0, stream,
                       X, diag, wlin_p, wtcn_p, aux, out);
}

// Round 6
// 308.419 us; speedup vs baseline: 1.1177x; 1.1135x over previous
//
#include <hip/hip_runtime.h>
#include <hip/hip_bf16.h>
#include <stdint.h>

// Problem constants: N=16, T=512, H=C=O=64, K=9, E=256
typedef float f32x4 __attribute__((ext_vector_type(4)));
typedef __bf16 bf16x8 __attribute__((ext_vector_type(8)));
typedef __bf16 bf16x4 __attribute__((ext_vector_type(4)));
typedef unsigned short u16;
typedef unsigned int u32;

__device__ __forceinline__ u16 f2bf(float f) {
    u32 u = __float_as_uint(f);
    u32 r = (u + 0x7fffu + ((u >> 16) & 1u)) >> 16;
    return (u16)r;
}

// DPP row_ror:N within 16-lane rows — VALU-pipe lane rotate (no LDS traffic)
template <int CTRL>
__device__ __forceinline__ float rrot(float x) {
    int r = __builtin_amdgcn_update_dpp(0, __builtin_bit_cast(int, x), CTRL, 0xF, 0xF, false);
    return __builtin_bit_cast(float, r);
}
__device__ __forceinline__ float rowsum16(float p) {
    p += rrot<0x128>(p);  // ror 8
    p += rrot<0x124>(p);  // ror 4
    p += rrot<0x122>(p);  // ror 2
    p += rrot<0x121>(p);  // ror 1
    return p;
}

// ---------------------------------------------------------------- k_attn
// (r3-proven version, unchanged) Block = (n, 4 t's). Coalesced X loads; DPP
// row reduction for a1/a2; adj built in LDS from edges (transposed adjT);
// appended blocks: weight pack (BN-gamma pre-scaled) + aux constants.
#define NB_ATTN 2048

__global__ __launch_bounds__(256) void k_attn(
    const float* __restrict__ X, const int* __restrict__ edges,
    const float* __restrict__ w1g, const float* __restrict__ b1g,
    const float* __restrict__ w2g, const float* __restrict__ b2g,
    const float* __restrict__ Wlin, const float* __restrict__ Wtcn,
    const float* __restrict__ blin, const float* __restrict__ g1,
    const float* __restrict__ be1, const float* __restrict__ btcn,
    const float* __restrict__ g2, const float* __restrict__ be2,
    u16* __restrict__ wlin_p, u16* __restrict__ wtcn_p,
    float* __restrict__ aux, float* __restrict__ diag) {
    const int tid = threadIdx.x;
    const int bid = blockIdx.x;
    const float rsf = 1.0f / sqrtf(1.0f + 1e-5f);

    if (bid >= NB_ATTN) {
        int idx = (bid - NB_ATTN) * 256 + tid;
        if (idx < 4096) {
            int jj = idx & 7, l = (idx >> 3) & 63, j = (idx >> 9) & 3, s = idx >> 11;
            int o = j * 16 + (l & 15);
            int c = s * 32 + (l >> 4) * 8 + jj;
            wlin_p[idx] = f2bf(Wlin[o * 64 + c] * (g1[o] * rsf));
        }
        int i2 = idx - 4096;
        if (i2 >= 0 && i2 < 36864) {
            int jj = i2 & 7, l = (i2 >> 3) & 63, j = (i2 >> 9) & 3, s = (i2 >> 11) & 1, kk = i2 >> 12;
            int o = j * 16 + (l & 15);
            int op = s * 32 + (l >> 4) * 8 + jj;
            wtcn_p[i2] = f2bf(Wtcn[(o * 64 + op) * 9 + kk] * (g2[o] * rsf));
        }
        if (idx >= 40960 && tid < 64) {
            aux[tid] = blin[tid] * g1[tid] * rsf;
            aux[64 + tid] = be1[tid];
            aux[128 + tid] = btcn[tid] * g2[tid] * rsf + be2[tid];
        }
        return;
    }

    __shared__ __align__(16) float adjT[64 * 65];
    __shared__ __align__(16) float A1s[4][64], A2s[4][64];

    const int n = bid >> 7;
    const int tg = bid & 127;
    const int w = tid >> 6, l = tid & 63;
    const int t = tg * 4 + w;
    const int c4 = l & 15, q = l >> 4;

    {
        f32x4 z4 = {0.f, 0.f, 0.f, 0.f};
        for (int i = tid; i < 1040; i += 256) *(f32x4*)(&adjT[i * 4]) = z4;
    }
    __syncthreads();
    {
        int r = edges[n * 512 + tid];
        int c = edges[n * 512 + 256 + tid];
        atomicAdd(&adjT[c * 65 + r], 1.0f);
    }

    const float* Xt = X + (size_t)(n * 512 + t) * 4096;
    const float4 w1v = *(const float4*)(w1g + c4 * 4);
    const float4 w2v = *(const float4*)(w2g + c4 * 4);
    float a1h = 0.f, a2h = 0.f;
#pragma unroll 8
    for (int i = 0; i < 16; i++) {
        float4 xv = *(const float4*)(Xt + (i * 64 + l) * 4);
        float p1 = xv.x * w1v.x + xv.y * w1v.y + xv.z * w1v.z + xv.w * w1v.w;
        float p2 = xv.x * w2v.x + xv.y * w2v.y + xv.z * w2v.z + xv.w * w2v.w;
        p1 = rowsum16(p1);
        p2 = rowsum16(p2);
        if (c4 == i) { a1h = p1; a2h = p2; }
    }
    {
        int hh = c4 * 4 + q;
        A1s[w][hh] = a1h + b1g[0];
        A2s[w][hh] = a2h + b2g[0];
    }
    __syncthreads();

    {
        float a2 = A2s[w][l];
        float num = 0.f, den = 0.f;
#pragma unroll
        for (int k4 = 0; k4 < 16; k4++) {
            float4 a1v = *(const float4*)(&A1s[w][k4 * 4]);
#pragma unroll
            for (int j = 0; j < 4; j++) {
                int k = k4 * 4 + j;
                float s = ((const float*)&a1v)[j] + a2;
                s = fmaxf(s, 0.01f * s);
                float e = __expf(s);
                den += e;
                num = fmaf(adjT[k * 65 + l], e, num);
            }
        }
        diag[((size_t)(n * 64 + l)) * 512 + t] = num / den + 1.0f;
    }
}

// ---------------------------------------------------------------- k_gcn_tcn
// One block per (n, h, half-T=256). Staged rows r=0..271 <-> t=tb-4+r
// (272 incl. halo+tile pad). LDS ~39KB -> 4 blocks/CU. G1: 17 m-tiles over
// 4 waves (support GEMM in place, BN1 pre-scaled). G2: wave w -> output
// rows [64w,64w+64): 4 m-tiles share each wtcn b-fragment (b-L2 traffic
// halved vs 128-row tile). Epilogue keeps the full-256B-row write pattern
// (partial-line writes double HBM write traffic — r5 lesson).
__global__ __launch_bounds__(256, 4) void k_gcn_tcn(
    const float* __restrict__ X, const float* __restrict__ diag,
    const u16* __restrict__ wlin_p, const u16* __restrict__ wtcn_p,
    const float* __restrict__ aux, float* __restrict__ out) {
    __shared__ __align__(16) u16 As[272 * 72];  // row r <-> t = tb-4+r, pad 72
    __shared__ float DGs[272];

    const int tid = threadIdx.x;
    const int bid = blockIdx.x;
    const int n = bid >> 7, h = (bid >> 1) & 63, tb = (bid & 1) * 256;
    const float* Xbase = X + ((size_t)(n * 512) * 64 + h) * 64;  // + t*4096 + c

    const int w = tid >> 6, l = tid & 63;
    const int col = l & 15, q = l >> 4;
    const f32x4 zv = {0.f, 0.f, 0.f, 0.f};

    // per-lane epilogue constants first (independent loads, hide under stage)
    float blp[4], bb1[4], cc2[4];
#pragma unroll
    for (int j = 0; j < 4; j++) {
        int o = 16 * j + col;
        blp[j] = aux[o];
        bb1[j] = aux[64 + o];
        cc2[j] = aux[128 + o];
    }
    // DG rows (L2-resident diag)
#pragma unroll
    for (int i = 0; i < 2; i++) {
        int idx = tid + 256 * i;
        if (idx < 272) {
            int tg = tb - 4 + idx;
            DGs[idx] = (tg >= 0 && tg < 512) ? diag[((size_t)(n * 64 + h)) * 512 + tg] : 0.f;
        }
    }

    // stage X (f32 -> bf16 via v_cvt_pk), zero outside [0,512); 17 loads in
    // flight per thread -> high MLP
#pragma unroll
    for (int i = 0; i < 17; i++) {
        int idx = tid + 256 * i;  // 272 rows * 16 quads = 4352
        int r = idx >> 4, c4 = idx & 15;
        int tg = tb - 4 + r;
        float4 xv = make_float4(0.f, 0.f, 0.f, 0.f);
        if (tg >= 0 && tg < 512) xv = *(const float4*)(Xbase + (size_t)tg * 4096 + c4 * 4);
        bf16x4 pk;
        pk[0] = (__bf16)xv.x; pk[1] = (__bf16)xv.y;
        pk[2] = (__bf16)xv.z; pk[3] = (__bf16)xv.w;
        *(bf16x4*)(&As[r * 72 + c4 * 4]) = pk;
    }
    __syncthreads();

    // support GEMM, z written in place over X rows (wave-private m-tiles)
    for (int mt = w; mt < 17; mt += 4) {
        f32x4 acc[4] = {zv, zv, zv, zv};
#pragma unroll
        for (int s = 0; s < 2; s++) {
            bf16x8 a = *(const bf16x8*)(&As[(16 * mt + col) * 72 + s * 32 + q * 8]);
#pragma unroll
            for (int j = 0; j < 4; j++) {
                bf16x8 b = *(const bf16x8*)(&wlin_p[((s * 4 + j) * 64 + l) * 8]);
                acc[j] = __builtin_amdgcn_mfma_f32_16x16x32_bf16(a, b, acc[j], 0, 0, 0);
            }
        }
#pragma unroll
        for (int j = 0; j < 4; j++) {
#pragma unroll
            for (int rr = 0; rr < 4; rr++) {
                int row = 16 * mt + q * 4 + rr;
                int tg = tb - 4 + row;
                float v = fmaf(acc[j][rr] + blp[j], DGs[row], bb1[j]);
                v = v > 0.f ? v : 0.f;
                if (tg < 0 || tg >= 512) v = 0.f;  // conv halo must be zero
                __bf16 bv = (__bf16)v;
                As[row * 72 + 16 * j + col] = __builtin_bit_cast(u16, bv);
            }
        }
    }
    __syncthreads();

    // temporal conv: wave w -> output local rows [64w, 64w+64); each
    // b-fragment reused across 4 m-tiles (halves wtcn L2 traffic)
    f32x4 acc2[4][4];  // [mt][j]
#pragma unroll
    for (int mt = 0; mt < 4; mt++)
#pragma unroll
        for (int j = 0; j < 4; j++) acc2[mt][j] = zv;

    for (int kk = 0; kk < 9; kk++) {
#pragma unroll
        for (int s = 0; s < 2; s++) {
            bf16x8 b[4];
#pragma unroll
            for (int j = 0; j < 4; j++)
                b[j] = *(const bf16x8*)(&wtcn_p[(((kk * 2 + s) * 4 + j) * 64 + l) * 8]);
#pragma unroll
            for (int mt = 0; mt < 4; mt++) {
                bf16x8 a = *(const bf16x8*)(&As[(64 * w + 16 * mt + col + kk) * 72 + s * 32 + q * 8]);
#pragma unroll
                for (int j = 0; j < 4; j++)
                    acc2[mt][j] = __builtin_amdgcn_mfma_f32_16x16x32_bf16(a, b[j], acc2[mt][j], 0, 0, 0);
            }
        }
    }

    // epilogue: +const (BN2 pre-folded) + f32 residual (L2-warm from stage)
    // + ReLU; j-loop covers the full 256B row per (t,h) -> full-line writes
#pragma unroll
    for (int mt = 0; mt < 4; mt++) {
        float res[4][4];
#pragma unroll
        for (int rr = 0; rr < 4; rr++) {
            int tt = tb + 64 * w + 16 * mt + 4 * q + rr;
#pragma unroll
            for (int j = 0; j < 4; j++)
                res[j][rr] = X[((size_t)(n * 512 + tt) * 64 + h) * 64 + 16 * j + col];
        }
#pragma unroll
        for (int rr = 0; rr < 4; rr++) {
            int tt = tb + 64 * w + 16 * mt + 4 * q + rr;
#pragma unroll
            for (int j = 0; j < 4; j++) {
                size_t off = ((size_t)(n * 512 + tt) * 64 + h) * 64 + 16 * j + col;
                float v = acc2[mt][j][rr] + cc2[j] + res[j][rr];
                out[off] = v > 0.f ? v : 0.f;
            }
        }
    }
}

// ---------------------------------------------------------------- launch
extern "C" void kernel_launch(void* const* d_in, const int* in_sizes, int n_in,
                              void* d_out, int out_size, void* d_ws, size_t ws_size,
                              hipStream_t stream) {
    const float* X    = (const float*)d_in[0];
    const int*  edges = (const int*)d_in[1];
    const float* w1   = (const float*)d_in[2];
    const float* b1   = (const float*)d_in[3];
    const float* w2   = (const float*)d_in[4];
    const float* b2   = (const float*)d_in[5];
    const float* Wlin = (const float*)d_in[6];
    const float* blin = (const float*)d_in[7];
    const float* g1   = (const float*)d_in[8];
    const float* be1  = (const float*)d_in[9];
    const float* Wtcn = (const float*)d_in[10];
    const float* btcn = (const float*)d_in[11];
    const float* g2   = (const float*)d_in[12];
    const float* be2  = (const float*)d_in[13];
    float* out = (float*)d_out;

    char* ws = (char*)d_ws;
    u16*   wlin_p = (u16*)ws;                          // 8192 B
    u16*   wtcn_p = (u16*)(ws + 8192);                 // 73728 B
    float* aux    = (float*)(ws + 8192 + 73728);       // 1024 B
    float* diag   = (float*)(ws + 8192 + 73728 + 1024);// 2097152 B

    hipLaunchKernelGGL(k_attn, dim3(NB_ATTN + 161), dim3(256), 0, stream,
                       X, edges, w1, b1, w2, b2, Wlin, Wtcn,
                       blin, g1, be1, btcn, g2, be2,
                       wlin_p, wtcn_p, aux, diag);
    hipLaunchKernelGGL(k_gcn_tcn, dim3(16 * 64 * 2), dim3(256), 0, stream,
                       X, diag, wlin_p, wtcn_p, aux, out);
}